// Round 9
// baseline (500.320 us; speedup 1.0000x reference)
//
#include <hip/hip_runtime.h>

// LSTMForecaster: B=4096, T=512, D=1, H=64, 2 layers + FC(64->1).
// R25 = R24 RESUBMITTED byte-identical (Round 8 was an infra failure:
//   "MI355X container failed twice", no test/counter output). Audit found no
//   hang/fault path: uniform barrier counts, LDS in-bounds, frag layouts
//   identical to proven R18/R19 conventions, ~200 VGPR @ 1 wave/SIMD.
// R24 = BATCH-OWNED WAVE STRUCTURE (full rewrite of the decomposition).
//   Evidence: R17/18/21/23 all failed to remove ~700 bubble cyc/step because
//   4 waves/SIMD serialize in the quarter-rate trans pipe (512 cyc/SIMD) and
//   LDS pipe (48 b128/step) no matter the sync mechanism. Root cause:
//   unit-sliced ownership -> every wave needs every wave's h each step.
//   Flip: each wave owns ALL its layer-half's units for the block's 16
//   batches -> layer recurrence is wave-private. 4 waves (L0a:u0-31,
//   L0b:u32-63, L1a, L1b), 256 thr, 1 wave/SIMD (launch_bounds(256,1),
//   weights resident in VGPR). One s_barrier per step, R19's skew
//   (iter tt: L0->h0(tt), L1->h1(tt-1)). h via 2-slot LDS ping-pong in
//   B-frag layout (XOR chunk swizzle = proven roff pattern). x-proj + bias
//   folded into an extra MFMA as bf16 hi/lo pairs (err ~2^-17).
//   Per step per wave: 24 (L0) / 40 (L1) MFMA, 4 cell2, 2-4 b128 reads.
//   Predicted: ~210-280us; Occupancy ~12% (by design); VGPR ~200-230;
//   bank conflicts <3e6; absmax ~6e-5. Revert point: R19 (420us).

#define TT 512
#define HH 64
#define NB 16
#define XP 516

typedef __bf16 bf16_t;
typedef bf16_t bf16x8 __attribute__((ext_vector_type(8)));
typedef float  f32x4  __attribute__((ext_vector_type(4)));
typedef float  f32x2  __attribute__((ext_vector_type(2)));

#define MFMA(A, B, C) __builtin_amdgcn_mfma_f32_16x16x32_bf16((A), (B), (C), 0, 0, 0)
#define RCPF(x) __builtin_amdgcn_rcpf(x)

#if __has_builtin(__builtin_amdgcn_exp2f)
#define EXP2F(x) __builtin_amdgcn_exp2f(x)
#else
__device__ __forceinline__ float EXP2F(float x) {
    float r;
    asm volatile("v_exp_f32 %0, %1" : "=v"(r) : "v"(x));
    return r;
}
#endif

#define SC_IFO (-1.4426950408889634f)   // -log2(e)
#define SC_G   ( 2.8853900817779268f)   // +2*log2(e)

__device__ __forceinline__ unsigned short f32_to_bf16_rne(float f) {
    unsigned int u = __builtin_bit_cast(unsigned int, f);
    unsigned int r = u + 0x7fffu + ((u >> 16) & 1u);
    return (unsigned short)(r >> 16);
}
__device__ __forceinline__ bf16_t bits_to_bf16(unsigned short u) {
    return __builtin_bit_cast(bf16_t, u);
}
__device__ __forceinline__ float bf16_bits_to_f32(unsigned short u) {
    unsigned int v = ((unsigned int)u) << 16;
    return __builtin_bit_cast(float, v);
}
// single-term weight frag with per-row scale folded in (RNE)
__device__ __forceinline__ void build_frag_scaled(const float* __restrict__ p, float sc,
                                                  bf16x8& w) {
    const float4 a = *(const float4*)p;
    const float4 b = *(const float4*)(p + 4);
    float v[8] = {a.x, a.y, a.z, a.w, b.x, b.y, b.z, b.w};
#pragma unroll
    for (int jj = 0; jj < 8; ++jj)
        w[jj] = bits_to_bf16(f32_to_bf16_rne(v[jj] * sc));
}

__device__ __forceinline__ f32x2 exp2v(f32x2 v) {
    f32x2 r; r[0] = EXP2F(v[0]); r[1] = EXP2F(v[1]); return r;
}
__device__ __forceinline__ f32x2 rcpv(f32x2 v) {
    f32x2 r; r[0] = RCPF(v[0]); r[1] = RCPF(v[1]); return r;
}
// Two cells on PRE-SCALED gates (is,fs,os scaled -log2e; gs scaled +2log2e).
__device__ __forceinline__ f32x2 cell2(const f32x4 a0, const f32x4 a1, f32x2* c) {
    f32x2 is = {a0[0], a1[0]}, fs = {a0[1], a1[1]};
    f32x2 gs = {a0[2], a1[2]}, os = {a0[3], a1[3]};
    const f32x2 pf = exp2v(fs);
    const f32x2 fg = rcpv(1.0f + pf);
    const f32x2 pi = exp2v(is);
    const f32x2 e2 = exp2v(gs);
    const f32x2 z  = (e2 - 1.0f) * rcpv((1.0f + pi) * (1.0f + e2));
    *c = fg * (*c) + z;
    const f32x2 po  = exp2v(os);
    const f32x2 e2c = exp2v((*c) * SC_G);
    return (e2c - 1.0f) * rcpv((1.0f + po) * (1.0f + e2c));
}

// per-iteration lockstep: drain LDS writes, hw barrier, fence the compiler
#define STEP_BARRIER()                                                          \
    do {                                                                        \
        asm volatile("s_waitcnt lgkmcnt(0)" ::: "memory");                      \
        __builtin_amdgcn_s_barrier();                                           \
        asm volatile("" ::: "memory");                                          \
    } while (0)

__global__ __launch_bounds__(256, 1)
void lstm_1t_kernel(const float* __restrict__ x,
                    const float* __restrict__ Wih0, const float* __restrict__ Whh0,
                    const float* __restrict__ bih0, const float* __restrict__ bhh0,
                    const float* __restrict__ Wih1, const float* __restrict__ Whh1,
                    const float* __restrict__ bih1, const float* __restrict__ bhh1,
                    const float* __restrict__ Wfc,  const float* __restrict__ bfc,
                    float* __restrict__ out)
{
    __shared__ float xbuf[NB][XP];                   // 33 KB
    __shared__ unsigned short h0s[2][NB][64];        // 4 KB ping-pong, B-layout
    __shared__ unsigned short h1s[2][NB][64];        // 4 KB ping-pong, B-layout
    __shared__ float h1fin[HH][NB + 1];              // 4.25 KB

    const int tid  = threadIdx.x;
    const int wv   = tid >> 6;       // 0:L0a 1:L0b 2:L1a 3:L1b
    const int lane = tid & 63;
    const int c    = lane & 15;      // batch col (N of B/D frag; M-row of A frag)
    const int q    = lane >> 4;      // k-chunk (A/B); D row group
    const int c7   = c & 7;
    const int b0   = blockIdx.x * NB;
    const bool isL0 = (wv < 2);
    const int jbase = (wv & 1) * 2;  // unit-tile j in {jbase, jbase+1}; units 16j..16j+15

    // ---- stage x (coalesced float4) ----
    for (int i = tid; i < NB * TT / 4; i += 256) {
        const int b  = i >> 7;
        const int t4 = i & 127;
        *(float4*)&xbuf[b][t4 * 4] = *(const float4*)&x[(size_t)(b0 + b) * TT + t4 * 4];
    }
    // ---- zero h slots (h(-1)/h(-2) read from zeroed slots) ----
    for (int i = tid; i < 2 * NB * 64; i += 256) {
        (&h0s[0][0][0])[i] = 0;
        (&h1s[0][0][0])[i] = 0;
    }

    // ---- B-frag read offsets (shorts): chunk (4kt+q) stored at (chunk^c7) ----
    int roff[2];
#pragma unroll
    for (int kt = 0; kt < 2; ++kt)
        roff[kt] = c * 64 + (((4 * kt + q) ^ c7) * 8);
    // ---- transpose-write offsets (shorts, b64): unit u=16j+4q+r ----
    //      chunk v = 2j+(q>>1) at (v^c7), within-chunk 4(q&1)+r
    int woff[2];
#pragma unroll
    for (int jj = 0; jj < 2; ++jj) {
        const int j = jbase + jj;
        woff[jj] = c * 64 + (((2 * j + (q >> 1)) ^ c7) * 8) + 4 * (q & 1);
    }

    unsigned short* const H0 = &h0s[0][0][0];
    unsigned short* const H1 = &h1s[0][0][0];

    __syncthreads();     // staging + zeroed slots visible

    if (isL0) {
        // ===== L0 wave: units [32(wv&1), 32(wv&1)+32), all 4 gates, 16 batches =====
        // A-tile (g,j): rows 64g+16j+(lane&15); D reg r, lane(c,q) -> unit 16j+4q+r, batch c
        bf16x8 Wf[2][4][2];      // [jj][g][kt] Whh0, scale folded
        bf16x8 F3[2][4];         // [jj][g] x-proj+bias A-frag: {wxh,wxh,wxl,bh,bl,0,0,0}
#pragma unroll
        for (int jj = 0; jj < 2; ++jj) {
            const int j = jbase + jj;
#pragma unroll
            for (int g = 0; g < 4; ++g) {
                const int row = 64 * g + 16 * j + c;
                const float sc = (g == 2) ? SC_G : SC_IFO;
#pragma unroll
                for (int kt = 0; kt < 2; ++kt)
                    build_frag_scaled(&Whh0[row * HH + kt * 32 + q * 8], sc, Wf[jj][g][kt]);
                const float wxs = Wih0[row] * sc;
                const float bbs = (bih0[row] + bhh0[row]) * sc;
                const unsigned short wxh = f32_to_bf16_rne(wxs);
                const unsigned short wxl = f32_to_bf16_rne(wxs - bf16_bits_to_f32(wxh));
                const unsigned short bh  = f32_to_bf16_rne(bbs);
                const unsigned short bl  = f32_to_bf16_rne(bbs - bf16_bits_to_f32(bh));
                bf16x8 f;
#pragma unroll
                for (int e = 0; e < 8; ++e) f[e] = bits_to_bf16(0);
                if (q == 0) {
                    f[0] = bits_to_bf16(wxh); f[1] = bits_to_bf16(wxh);
                    f[2] = bits_to_bf16(wxl);
                    f[3] = bits_to_bf16(bh);  f[4] = bits_to_bf16(bl);
                }
                F3[jj][g] = f;
            }
        }

        f32x2 cst[4] = {{0.f, 0.f}, {0.f, 0.f}, {0.f, 0.f}, {0.f, 0.f}};

#pragma unroll 1
        for (int tt = 0; tt <= TT; ++tt) {
            if (tt < TT) {
                // h0(tt-1) from slot (tt-1)&1 (tt=0 -> zeroed slot 1)
                const int rs = ((tt - 1) & 1) * (NB * 64);
                const bf16x8 h0f0 = *(const bf16x8*)(H0 + rs + roff[0]);
                const bf16x8 h0f1 = *(const bf16x8*)(H0 + rs + roff[1]);

                // B-frag3: {xh, xl, xh, 1, 1, 0,0,0} in chunk 0
                const float xv = xbuf[c][tt];
                const unsigned short xh = f32_to_bf16_rne(xv);
                const unsigned short xl = f32_to_bf16_rne(xv - bf16_bits_to_f32(xh));
                bf16x8 b3;
#pragma unroll
                for (int e = 0; e < 8; ++e) b3[e] = bits_to_bf16(0);
                if (q == 0) {
                    b3[0] = bits_to_bf16(xh); b3[1] = bits_to_bf16(xl);
                    b3[2] = bits_to_bf16(xh);
                    b3[3] = bits_to_bf16(0x3F80); b3[4] = bits_to_bf16(0x3F80);
                }

                const int ws = (tt & 1) * (NB * 64);
#pragma unroll
                for (int jj = 0; jj < 2; ++jj) {
                    f32x4 acc[4];
#pragma unroll
                    for (int g = 0; g < 4; ++g) {
                        f32x4 z = {0.f, 0.f, 0.f, 0.f};
                        z = MFMA(F3[jj][g], b3, z);              // x-proj + bias
                        z = MFMA(Wf[jj][g][1], h0f1, z);         // Whh0 . h0 (k 32-63)
                        acc[g] = MFMA(Wf[jj][g][0], h0f0, z);    // Whh0 . h0 (k 0-31)
                    }
                    const f32x4 g0 = {acc[0][0], acc[1][0], acc[2][0], acc[3][0]};
                    const f32x4 g1 = {acc[0][1], acc[1][1], acc[2][1], acc[3][1]};
                    const f32x4 g2 = {acc[0][2], acc[1][2], acc[2][2], acc[3][2]};
                    const f32x4 g3 = {acc[0][3], acc[1][3], acc[2][3], acc[3][3]};
                    const f32x2 hvA = cell2(g0, g1, &cst[jj * 2]);
                    const f32x2 hvB = cell2(g2, g3, &cst[jj * 2 + 1]);
                    const unsigned int lo = (unsigned int)f32_to_bf16_rne(hvA[0]) |
                                            ((unsigned int)f32_to_bf16_rne(hvA[1]) << 16);
                    const unsigned int hi = (unsigned int)f32_to_bf16_rne(hvB[0]) |
                                            ((unsigned int)f32_to_bf16_rne(hvB[1]) << 16);
                    uint2 v; v.x = lo; v.y = hi;
                    *(uint2*)(H0 + ws + woff[jj]) = v;           // units 16j+4q+{0..3}, batch c
                }
            }
            STEP_BARRIER();
        }
    } else {
        // ===== L1 wave: units [32(wv&1), +32) of layer 1, skew: iter tt -> h1(tt-1) =====
        bf16x8 Wi[2][4][2];      // Wih1 (eats h0), scale folded
        bf16x8 Wh[2][4][2];      // Whh1 (eats h1), scale folded
        bf16x8 BA[2][4];         // bias A-frag: {bh, bl, 0...}
#pragma unroll
        for (int jj = 0; jj < 2; ++jj) {
            const int j = jbase + jj;
#pragma unroll
            for (int g = 0; g < 4; ++g) {
                const int row = 64 * g + 16 * j + c;
                const float sc = (g == 2) ? SC_G : SC_IFO;
#pragma unroll
                for (int kt = 0; kt < 2; ++kt) {
                    build_frag_scaled(&Wih1[row * HH + kt * 32 + q * 8], sc, Wi[jj][g][kt]);
                    build_frag_scaled(&Whh1[row * HH + kt * 32 + q * 8], sc, Wh[jj][g][kt]);
                }
                const float bbs = (bih1[row] + bhh1[row]) * sc;
                const unsigned short bh = f32_to_bf16_rne(bbs);
                const unsigned short bl = f32_to_bf16_rne(bbs - bf16_bits_to_f32(bh));
                bf16x8 f;
#pragma unroll
                for (int e = 0; e < 8; ++e) f[e] = bits_to_bf16(0);
                if (q == 0) { f[0] = bits_to_bf16(bh); f[1] = bits_to_bf16(bl); }
                BA[jj][g] = f;
            }
        }
        bf16x8 Bone;             // B-frag {1,1,0,...} in chunk 0
#pragma unroll
        for (int e = 0; e < 8; ++e) Bone[e] = bits_to_bf16(0);
        if (q == 0) { Bone[0] = bits_to_bf16(0x3F80); Bone[1] = bits_to_bf16(0x3F80); }

        f32x2 cst[4] = {{0.f, 0.f}, {0.f, 0.f}, {0.f, 0.f}, {0.f, 0.f}};

#pragma unroll 1
        for (int tt = 0; tt <= TT; ++tt) {
            if (tt >= 1) {
                const int tm = tt - 1;               // computing h1(tm)
                const int rs0 = (tm & 1) * (NB * 64);        // h0(tm), written iter tm
                const int rs1 = ((tm - 1) & 1) * (NB * 64);  // h1(tm-1); tm=0 -> zeroed
                const bf16x8 h0f0 = *(const bf16x8*)(H0 + rs0 + roff[0]);
                const bf16x8 h0f1 = *(const bf16x8*)(H0 + rs0 + roff[1]);
                const bf16x8 h1f0 = *(const bf16x8*)(H1 + rs1 + roff[0]);
                const bf16x8 h1f1 = *(const bf16x8*)(H1 + rs1 + roff[1]);

                const int ws = (tm & 1) * (NB * 64);
#pragma unroll
                for (int jj = 0; jj < 2; ++jj) {
                    f32x4 acc[4];
#pragma unroll
                    for (int g = 0; g < 4; ++g) {
                        f32x4 z = {0.f, 0.f, 0.f, 0.f};
                        z = MFMA(BA[jj][g], Bone, z);            // bias
                        z = MFMA(Wh[jj][g][1], h1f1, z);         // Whh1 . h1(tm-1)
                        z = MFMA(Wh[jj][g][0], h1f0, z);
                        z = MFMA(Wi[jj][g][1], h0f1, z);         // Wih1 . h0(tm)
                        acc[g] = MFMA(Wi[jj][g][0], h0f0, z);
                    }
                    const f32x4 g0 = {acc[0][0], acc[1][0], acc[2][0], acc[3][0]};
                    const f32x4 g1 = {acc[0][1], acc[1][1], acc[2][1], acc[3][1]};
                    const f32x4 g2 = {acc[0][2], acc[1][2], acc[2][2], acc[3][2]};
                    const f32x4 g3 = {acc[0][3], acc[1][3], acc[2][3], acc[3][3]};
                    const f32x2 hvA = cell2(g0, g1, &cst[jj * 2]);
                    const f32x2 hvB = cell2(g2, g3, &cst[jj * 2 + 1]);
                    if (tm == TT - 1) {              // exact fp32 h1(T-1) for FC
                        const int ub = 16 * (jbase + jj) + 4 * q;
                        h1fin[ub + 0][c] = hvA[0];
                        h1fin[ub + 1][c] = hvA[1];
                        h1fin[ub + 2][c] = hvB[0];
                        h1fin[ub + 3][c] = hvB[1];
                    }
                    const unsigned int lo = (unsigned int)f32_to_bf16_rne(hvA[0]) |
                                            ((unsigned int)f32_to_bf16_rne(hvA[1]) << 16);
                    const unsigned int hi = (unsigned int)f32_to_bf16_rne(hvB[0]) |
                                            ((unsigned int)f32_to_bf16_rne(hvB[1]) << 16);
                    uint2 v; v.x = lo; v.y = hi;
                    *(uint2*)(H1 + ws + woff[jj]) = v;
                }
            }
            STEP_BARRIER();
        }
    }

    __syncthreads();

    // ---- FC epilogue: out[b] = h1(T-1)[b] . Wfc + bfc ----
    if (tid < NB) {
        float sacc = bfc[0];
#pragma unroll
        for (int u = 0; u < HH; ++u) sacc = fmaf(h1fin[u][tid], Wfc[u], sacc);
        out[b0 + tid] = sacc;
    }
}

extern "C" void kernel_launch(void* const* d_in, const int* in_sizes, int n_in,
                              void* d_out, int out_size, void* d_ws, size_t ws_size,
                              hipStream_t stream) {
    const float* x    = (const float*)d_in[0];
    const float* Wih0 = (const float*)d_in[1];
    const float* Whh0 = (const float*)d_in[2];
    const float* bih0 = (const float*)d_in[3];
    const float* bhh0 = (const float*)d_in[4];
    const float* Wih1 = (const float*)d_in[5];
    const float* Whh1 = (const float*)d_in[6];
    const float* bih1 = (const float*)d_in[7];
    const float* bhh1 = (const float*)d_in[8];
    const float* Wfc  = (const float*)d_in[9];
    const float* bfc  = (const float*)d_in[10];

    lstm_1t_kernel<<<dim3(4096 / NB), dim3(256), 0, stream>>>(
        x, Wih0, Whh0, bih0, bhh0, Wih1, Whh1, bih1, bhh1, Wfc, bfc, (float*)d_out);
}

// Round 10
// 437.466 us; speedup vs baseline: 1.1437x; 1.1437x over previous
//
#include <hip/hip_runtime.h>

// LSTMForecaster: B=4096, T=512, D=1, H=64, 2 layers + FC(64->1).
// R26 = R19 reparameterized: 8 waves (4 L0 x 16u + 4 L1 x 16u), barrier
//   lockstep. The missing point in the (waves x units/wave) grid.
//   Evidence synthesis:
//     R19 16w/8u barrier: 1825 cyc/step. LDS arithmetic (85 B/cyc/CU, m134):
//       48 b128 reads/step = 49KB -> ~580 cyc LDS-pipe serial + ~200 writes
//       = the sticky ~700 "bubble" -> LDS-THROUGHPUT-bound.
//     R25 4w/64u: 2246 cyc, issue only ~690 -> ~1550 exposed latency at
//       1 wave/SIMD -> LATENCY-bound. R20 8w merged: 2060 (5-deep chains,
//       4 reads before any MFMA).
//   Sweet spot: 2 waves/SIMD, split roles, halved LDS traffic:
//     reads 24 b128 = 24.5KB -> ~290 cyc; MFMA/CU unchanged (96);
//     issue/SIMD ~670 (120 MFMA + 288 trans + ~260 VALU); light bodies,
//     mutual latency hiding. All formulas = proven R16/R19 (stride 16).
//   Predicted: 240-320us; MfmaUtil ~35-42; Occupancy ~25%; VGPR ~130;
//   absmax exactly 6.103516e-05. Revert point: R19 (420us).

#define TT 512
#define HH 64
#define NB 16
#define XP 516

typedef __bf16 bf16_t;
typedef bf16_t bf16x8 __attribute__((ext_vector_type(8)));
typedef float  f32x4  __attribute__((ext_vector_type(4)));
typedef float  f32x2  __attribute__((ext_vector_type(2)));

#define MFMA(A, B, C) __builtin_amdgcn_mfma_f32_16x16x32_bf16((A), (B), (C), 0, 0, 0)
#define RCPF(x) __builtin_amdgcn_rcpf(x)

#if __has_builtin(__builtin_amdgcn_exp2f)
#define EXP2F(x) __builtin_amdgcn_exp2f(x)
#else
__device__ __forceinline__ float EXP2F(float x) {
    float r;
    asm volatile("v_exp_f32 %0, %1" : "=v"(r) : "v"(x));
    return r;
}
#endif

#define SC_IFO (-1.4426950408889634f)   // -log2(e)
#define SC_G   ( 2.8853900817779268f)   // +2*log2(e)

__device__ __forceinline__ unsigned short f32_to_bf16_rne(float f) {
    unsigned int u = __builtin_bit_cast(unsigned int, f);
    unsigned int r = u + 0x7fffu + ((u >> 16) & 1u);
    return (unsigned short)(r >> 16);
}
__device__ __forceinline__ bf16_t bits_to_bf16(unsigned short u) {
    return __builtin_bit_cast(bf16_t, u);
}
// single-term weight frag with per-row scale folded in (RNE)
__device__ __forceinline__ void build_frag_scaled(const float* __restrict__ p, float sc,
                                                  bf16x8& w) {
    const float4 a = *(const float4*)p;
    const float4 b = *(const float4*)(p + 4);
    float v[8] = {a.x, a.y, a.z, a.w, b.x, b.y, b.z, b.w};
#pragma unroll
    for (int jj = 0; jj < 8; ++jj)
        w[jj] = bits_to_bf16(f32_to_bf16_rne(v[jj] * sc));
}

__device__ __forceinline__ f32x2 exp2v(f32x2 v) {
    f32x2 r; r[0] = EXP2F(v[0]); r[1] = EXP2F(v[1]); return r;
}
__device__ __forceinline__ f32x2 rcpv(f32x2 v) {
    f32x2 r; r[0] = RCPF(v[0]); r[1] = RCPF(v[1]); return r;
}
// Two cells on PRE-SCALED gates (is,fs,os scaled -log2e; gs scaled +2log2e).
__device__ __forceinline__ f32x2 cell2(const f32x4 a0, const f32x4 a1, f32x2* c) {
    f32x2 is = {a0[0], a1[0]}, fs = {a0[1], a1[1]};
    f32x2 gs = {a0[2], a1[2]}, os = {a0[3], a1[3]};
    const f32x2 pf = exp2v(fs);
    const f32x2 fg = rcpv(1.0f + pf);
    const f32x2 pi = exp2v(is);
    const f32x2 e2 = exp2v(gs);
    const f32x2 z  = (e2 - 1.0f) * rcpv((1.0f + pi) * (1.0f + e2));
    *c = fg * (*c) + z;
    const f32x2 po  = exp2v(os);
    const f32x2 e2c = exp2v((*c) * SC_G);
    return (e2c - 1.0f) * rcpv((1.0f + po) * (1.0f + e2c));
}

// per-iteration lockstep: drain LDS writes, hw barrier, fence the compiler
#define STEP_BARRIER()                                                          \
    do {                                                                        \
        asm volatile("s_waitcnt lgkmcnt(0)" ::: "memory");                      \
        __builtin_amdgcn_s_barrier();                                           \
        asm volatile("" ::: "memory");                                          \
    } while (0)

__global__ __launch_bounds__(512, 2)
void lstm_1t_kernel(const float* __restrict__ x,
                    const float* __restrict__ Wih0, const float* __restrict__ Whh0,
                    const float* __restrict__ bih0, const float* __restrict__ bhh0,
                    const float* __restrict__ Wih1, const float* __restrict__ Whh1,
                    const float* __restrict__ bih1, const float* __restrict__ bhh1,
                    const float* __restrict__ Wfc,  const float* __restrict__ bfc,
                    float* __restrict__ out)
{
    __shared__ float xbuf[NB][XP];                   // 33 KB
    __shared__ unsigned short h0r[8][NB][64];        // 16 KB ring, slot t&7
    __shared__ unsigned short h1r[2][NB][64];        // 4 KB ring, slot t&1
    __shared__ float h1fin[HH][NB + 1];              // 4.25 KB

    const int tid  = threadIdx.x;
    const int wv   = tid >> 6;       // 0..7: 0-3 L0 waves, 4-7 L1 waves
    const int lane = tid & 63;
    const int m    = lane & 15;      // batch col (B/C frag) & A-frag row-in-tile
    const int q    = lane >> 4;      // C-frag unit_local; A/B k-quad
    const int m7   = m & 7;
    const int b0   = blockIdx.x * NB;
    const bool isL0 = (wv < 4);

    // ---- stage x (coalesced float4) ----
    for (int i = tid; i < NB * TT / 4; i += 512) {
        const int b  = i >> 7;
        const int t4 = i & 127;
        *(float4*)&xbuf[b][t4 * 4] = *(const float4*)&x[(size_t)(b0 + b) * TT + t4 * 4];
    }
    // ---- zero rings (h(-1)/h(-2) served by zeroed slots) ----
    for (int i = tid; i < 8 * NB * 64; i += 512) (&h0r[0][0][0])[i] = 0;
    for (int i = tid; i < 2 * NB * 64; i += 512) (&h1r[0][0][0])[i] = 0;

    // ---- per-lane read offsets (shorts within one slot = 1024) ----
    int roff[2];
#pragma unroll
    for (int kt = 0; kt < 2; ++kt)
        roff[kt] = m * 64 + (((4 * kt + q) ^ m7) * 8);

    const int gate_m = m & 3;
    const float scA  = (gate_m == 2) ? SC_G : SC_IFO;
    unsigned short* const H0 = &h0r[0][0][0];
    unsigned short* const H1 = &h1r[0][0][0];

    __syncthreads();     // staging visible (drains vmcnt too)

    if (isL0) {
        // ===== L0 waves: units [16w,16w+16), 4 unit-major tiles, 8 MFMA =====
        const int w = wv;
        bf16x8 Ah[4][2];                    // [tau][kt] of Whh0 (single-term)
        f32x4 bb0s[4], wx0s[4];
        int woff[4];
#pragma unroll
        for (int tau = 0; tau < 4; ++tau) {
            const int rowA = 64 * gate_m + 16 * w + 4 * tau + (m >> 2);
#pragma unroll
            for (int kt = 0; kt < 2; ++kt)
                build_frag_scaled(&Whh0[rowA * HH + kt * 32 + q * 8], scA, Ah[tau][kt]);
#pragma unroll
            for (int r = 0; r < 4; ++r) {
                const int row = 64 * r + 16 * w + 4 * tau + q;
                const float sc = (r == 2) ? SC_G : SC_IFO;
                bb0s[tau][r] = (bih0[row] + bhh0[row]) * sc;
                wx0s[tau][r] = Wih0[row] * sc;
            }
            const int u = 16 * w + 4 * tau + q;
            woff[tau] = m * 64 + (((u >> 3) ^ m7) * 8) + (u & 7);
        }

        f32x2 cA = {0.f, 0.f}, cB = {0.f, 0.f};

#pragma unroll 1
        for (int tt = 0; tt <= TT; ++tt) {
            if (tt < TT) {
                // h0(tt-1) guaranteed by last iteration's barrier (tt=0: zeroed slot 7)
                const int rs = ((tt - 1) & 7) * (NB * 64);
                bf16x8 h0[2];
                h0[0] = *(const bf16x8*)(H0 + rs + roff[0]);
                h0[1] = *(const bf16x8*)(H0 + rs + roff[1]);

                const float xv = xbuf[m][tt];
                f32x4 a[4];
#pragma unroll
                for (int tau = 0; tau < 4; ++tau) {
#pragma unroll
                    for (int r = 0; r < 4; ++r)
                        a[tau][r] = __builtin_fmaf(xv, wx0s[tau][r], bb0s[tau][r]);
                }

#pragma unroll
                for (int tau = 0; tau < 4; ++tau) {
                    f32x4 z = {0.f, 0.f, 0.f, 0.f};
                    a[tau] = MFMA(Ah[tau][0], h0[0], a[tau]);
                    z      = MFMA(Ah[tau][1], h0[1], z);
                    a[tau] = a[tau] + z;
                }

                const f32x2 hv0 = cell2(a[0], a[1], &cA);
                const f32x2 hv1 = cell2(a[2], a[3], &cB);

                const int ws = (tt & 7) * (NB * 64);
                H0[ws + woff[0]] = f32_to_bf16_rne(hv0[0]);
                H0[ws + woff[1]] = f32_to_bf16_rne(hv0[1]);
                H0[ws + woff[2]] = f32_to_bf16_rne(hv1[0]);
                H0[ws + woff[3]] = f32_to_bf16_rne(hv1[1]);
            }
            STEP_BARRIER();
        }
    } else {
        // ===== L1 waves: units [16u,16u+16), 4 tiles, 16 MFMA; skewed: iter tt -> h1(tt-1) =====
        const int uW = wv - 4;
        bf16x8 Ah[4][4];     // [tau][kt]: kt0-1 Wih1 (eats h0), kt2-3 Whh1 (eats h1)
        f32x4 bb1s[4];
        int woff[4], uu[4];
#pragma unroll
        for (int tau = 0; tau < 4; ++tau) {
            const int rowA = 64 * gate_m + 16 * uW + 4 * tau + (m >> 2);
#pragma unroll
            for (int kt = 0; kt < 2; ++kt)
                build_frag_scaled(&Wih1[rowA * HH + kt * 32 + q * 8], scA, Ah[tau][kt]);
#pragma unroll
            for (int kt = 0; kt < 2; ++kt)
                build_frag_scaled(&Whh1[rowA * HH + kt * 32 + q * 8], scA, Ah[tau][2 + kt]);
#pragma unroll
            for (int r = 0; r < 4; ++r) {
                const int row = 64 * r + 16 * uW + 4 * tau + q;
                const float sc = (r == 2) ? SC_G : SC_IFO;
                bb1s[tau][r] = (bih1[row] + bhh1[row]) * sc;
            }
            const int u = 16 * uW + 4 * tau + q;
            uu[tau]   = u;
            woff[tau] = m * 64 + (((u >> 3) ^ m7) * 8) + (u & 7);
        }

        f32x2 c1A = {0.f, 0.f}, c1B = {0.f, 0.f};

#pragma unroll 1
        for (int tt = 0; tt <= TT; ++tt) {
            if (tt >= 1) {
                const int tm = tt - 1;               // computing h1(tm)
                // h0(tm): written by L0 in iteration tm (1 barrier ago)
                // h1(tm-1): written by L1 in iteration tm (1 barrier ago); tm=0 -> zeroed
                const int rs0 = (tm & 7) * (NB * 64);
                const int rs1 = ((tm - 1) & 1) * (NB * 64);
                bf16x8 h0[2], h1[2];
                h0[0] = *(const bf16x8*)(H0 + rs0 + roff[0]);
                h0[1] = *(const bf16x8*)(H0 + rs0 + roff[1]);
                h1[0] = *(const bf16x8*)(H1 + rs1 + roff[0]);
                h1[1] = *(const bf16x8*)(H1 + rs1 + roff[1]);

                f32x4 a[4];
#pragma unroll
                for (int tau = 0; tau < 4; ++tau) {
                    a[tau] = MFMA(Ah[tau][0], h0[0], bb1s[tau]);   // Wih1 . h0(tm)
                    a[tau] = MFMA(Ah[tau][1], h0[1], a[tau]);
                    a[tau] = MFMA(Ah[tau][2], h1[0], a[tau]);      // + Whh1 . h1(tm-1)
                    a[tau] = MFMA(Ah[tau][3], h1[1], a[tau]);
                }

                const f32x2 hvA = cell2(a[0], a[1], &c1A);
                const f32x2 hvB = cell2(a[2], a[3], &c1B);
                if (tm == TT - 1) {                  // exact fp32 h1(T-1) for FC
                    h1fin[uu[0]][m] = hvA[0];
                    h1fin[uu[1]][m] = hvA[1];
                    h1fin[uu[2]][m] = hvB[0];
                    h1fin[uu[3]][m] = hvB[1];
                }
                const int ws = (tm & 1) * (NB * 64);
                H1[ws + woff[0]] = f32_to_bf16_rne(hvA[0]);
                H1[ws + woff[1]] = f32_to_bf16_rne(hvA[1]);
                H1[ws + woff[2]] = f32_to_bf16_rne(hvB[0]);
                H1[ws + woff[3]] = f32_to_bf16_rne(hvB[1]);
            }
            STEP_BARRIER();
        }
    }

    __syncthreads();

    // ---- FC epilogue: out[b] = h1(T-1)[b] . Wfc + bfc ----
    if (tid < NB) {
        float sacc = bfc[0];
#pragma unroll
        for (int u = 0; u < HH; ++u) sacc = fmaf(h1fin[u][tid], Wfc[u], sacc);
        out[b0 + tid] = sacc;
    }
}

extern "C" void kernel_launch(void* const* d_in, const int* in_sizes, int n_in,
                              void* d_out, int out_size, void* d_ws, size_t ws_size,
                              hipStream_t stream) {
    const float* x    = (const float*)d_in[0];
    const float* Wih0 = (const float*)d_in[1];
    const float* Whh0 = (const float*)d_in[2];
    const float* bih0 = (const float*)d_in[3];
    const float* bhh0 = (const float*)d_in[4];
    const float* Wih1 = (const float*)d_in[5];
    const float* Whh1 = (const float*)d_in[6];
    const float* bih1 = (const float*)d_in[7];
    const float* bhh1 = (const float*)d_in[8];
    const float* Wfc  = (const float*)d_in[9];
    const float* bfc  = (const float*)d_in[10];

    lstm_1t_kernel<<<dim3(4096 / NB), dim3(512), 0, stream>>>(
        x, Wih0, Whh0, bih0, bhh0, Wih1, Whh1, bih1, bhh1, Wfc, bfc, (float*)d_out);
}

// Round 11
// 434.480 us; speedup vs baseline: 1.1515x; 1.0069x over previous
//
#include <hip/hip_runtime.h>

// LSTMForecaster: B=4096, T=512, D=1, H=64, 2 layers + FC(64->1).
// R27 = R19 champion (16 waves: 8 L0 x 8u + 8 L1 x 8u, barrier lockstep,
//   402-420us) + CHAIN SURGERY:
//   1. L0 x-proj software-pipelined: next step's 16 FMAs issued BETWEEN the
//      h0 stores and the lgkm drain -> fills the write-retire window, and
//      post-barrier L0 starts directly at ds_read (chain head).
//   2. L1 MFMA 2+2 tree (R18's proven form): p=(bb+Wih.h0) || s=(Whh.h1),
//      a=p+s -> chain depth 2 MFMAs instead of 4 (~-50 cyc).
//   Evidence: grid over (waves x units) complete: 16w=402 < 8w-split=418 <
//   8w-merged=440 < 4w=480; LDS-traffic halving neutral -> wall = issue
//   (~1150 cyc, invariant) + ~700 serial chain/barrier exposure. Only
//   chain-latency cuts remain. Everything else byte-identical to R19.
//   Predicted: 370-405us; absmax exactly 6.103516e-05 (R18 order).
//   If >=405: structure at latency+issue floor. Revert point: R19.

#define TT 512
#define HH 64
#define NB 16
#define XP 516

typedef __bf16 bf16_t;
typedef bf16_t bf16x8 __attribute__((ext_vector_type(8)));
typedef float  f32x4  __attribute__((ext_vector_type(4)));
typedef float  f32x2  __attribute__((ext_vector_type(2)));

#define MFMA(A, B, C) __builtin_amdgcn_mfma_f32_16x16x32_bf16((A), (B), (C), 0, 0, 0)
#define RCPF(x) __builtin_amdgcn_rcpf(x)

#if __has_builtin(__builtin_amdgcn_exp2f)
#define EXP2F(x) __builtin_amdgcn_exp2f(x)
#else
__device__ __forceinline__ float EXP2F(float x) {
    float r;
    asm volatile("v_exp_f32 %0, %1" : "=v"(r) : "v"(x));
    return r;
}
#endif

#define SC_IFO (-1.4426950408889634f)   // -log2(e)
#define SC_G   ( 2.8853900817779268f)   // +2*log2(e)

__device__ __forceinline__ unsigned short f32_to_bf16_rne(float f) {
    unsigned int u = __builtin_bit_cast(unsigned int, f);
    unsigned int r = u + 0x7fffu + ((u >> 16) & 1u);
    return (unsigned short)(r >> 16);
}
__device__ __forceinline__ bf16_t bits_to_bf16(unsigned short u) {
    return __builtin_bit_cast(bf16_t, u);
}
// single-term weight frag with per-row scale folded in (RNE)
__device__ __forceinline__ void build_frag_scaled(const float* __restrict__ p, float sc,
                                                  bf16x8& w) {
    const float4 a = *(const float4*)p;
    const float4 b = *(const float4*)(p + 4);
    float v[8] = {a.x, a.y, a.z, a.w, b.x, b.y, b.z, b.w};
#pragma unroll
    for (int jj = 0; jj < 8; ++jj)
        w[jj] = bits_to_bf16(f32_to_bf16_rne(v[jj] * sc));
}

__device__ __forceinline__ f32x2 exp2v(f32x2 v) {
    f32x2 r; r[0] = EXP2F(v[0]); r[1] = EXP2F(v[1]); return r;
}
__device__ __forceinline__ f32x2 rcpv(f32x2 v) {
    f32x2 r; r[0] = RCPF(v[0]); r[1] = RCPF(v[1]); return r;
}
// Two cells on PRE-SCALED gates (is,fs,os scaled -log2e; gs scaled +2log2e).
__device__ __forceinline__ f32x2 cell2(const f32x4 a0, const f32x4 a1, f32x2* c) {
    f32x2 is = {a0[0], a1[0]}, fs = {a0[1], a1[1]};
    f32x2 gs = {a0[2], a1[2]}, os = {a0[3], a1[3]};
    const f32x2 pf = exp2v(fs);
    const f32x2 fg = rcpv(1.0f + pf);
    const f32x2 pi = exp2v(is);
    const f32x2 e2 = exp2v(gs);
    const f32x2 z  = (e2 - 1.0f) * rcpv((1.0f + pi) * (1.0f + e2));
    *c = fg * (*c) + z;
    const f32x2 po  = exp2v(os);
    const f32x2 e2c = exp2v((*c) * SC_G);
    return (e2c - 1.0f) * rcpv((1.0f + po) * (1.0f + e2c));
}

__global__ __launch_bounds__(1024, 4)
void lstm_1t_kernel(const float* __restrict__ x,
                    const float* __restrict__ Wih0, const float* __restrict__ Whh0,
                    const float* __restrict__ bih0, const float* __restrict__ bhh0,
                    const float* __restrict__ Wih1, const float* __restrict__ Whh1,
                    const float* __restrict__ bih1, const float* __restrict__ bhh1,
                    const float* __restrict__ Wfc,  const float* __restrict__ bfc,
                    float* __restrict__ out)
{
    __shared__ float xbuf[NB][XP];                   // 33 KB
    __shared__ unsigned short h0r[8][NB][64];        // 16 KB ring, slot t&7
    __shared__ unsigned short h1r[2][NB][64];        // 4 KB ring, slot t&1
    __shared__ float h1fin[HH][NB + 1];              // 4.25 KB

    const int tid  = threadIdx.x;
    const int wv   = tid >> 6;       // 0..15: 0-7 L0 waves, 8-15 L1 waves
    const int lane = tid & 63;
    const int m    = lane & 15;      // batch col (B/C frag) & A-frag row-in-tile
    const int q    = lane >> 4;      // C-frag unit_local; A/B k-quad
    const int m7   = m & 7;
    const int b0   = blockIdx.x * NB;
    const bool isL0 = (wv < 8);

    // ---- stage x (coalesced float4) ----
    for (int i = tid; i < NB * TT / 4; i += 1024) {
        const int b  = i >> 7;
        const int t4 = i & 127;
        *(float4*)&xbuf[b][t4 * 4] = *(const float4*)&x[(size_t)(b0 + b) * TT + t4 * 4];
    }
    // ---- zero rings (h(-1)/h(-2) served by zeroed slots) ----
    for (int i = tid; i < 8 * NB * 64; i += 1024) (&h0r[0][0][0])[i] = 0;
    for (int i = tid; i < 2 * NB * 64; i += 1024) (&h1r[0][0][0])[i] = 0;

    // ---- per-lane read offsets (shorts within one slot = 1024) ----
    int roff[2];
#pragma unroll
    for (int kt = 0; kt < 2; ++kt)
        roff[kt] = m * 64 + (((4 * kt + q) ^ m7) * 8);

    const int gate_m = m & 3;
    const float scA  = (gate_m == 2) ? SC_G : SC_IFO;
    unsigned short* const H0 = &h0r[0][0][0];
    unsigned short* const H1 = &h1r[0][0][0];

    __syncthreads();     // staging visible (drains vmcnt too)

    if (isL0) {
        // ===== L0 waves: units [8w,8w+8), 2 unit-major tiles, 4 MFMA =====
        const int w = wv;
        bf16x8 Ah[2][2];                    // [tau][kt] of Whh0 (single-term)
        f32x4 bb0s[2], wx0s[2];
        int woff[2];
#pragma unroll
        for (int tau = 0; tau < 2; ++tau) {
            const int rowA = 64 * gate_m + 8 * w + 4 * tau + (m >> 2);
#pragma unroll
            for (int kt = 0; kt < 2; ++kt)
                build_frag_scaled(&Whh0[rowA * HH + kt * 32 + q * 8], scA, Ah[tau][kt]);
#pragma unroll
            for (int r = 0; r < 4; ++r) {
                const int row = 64 * r + 8 * w + 4 * tau + q;
                const float sc = (r == 2) ? SC_G : SC_IFO;
                bb0s[tau][r] = (bih0[row] + bhh0[row]) * sc;
                wx0s[tau][r] = Wih0[row] * sc;
            }
            const int u = 8 * w + 4 * tau + q;
            woff[tau] = m * 64 + (((u >> 3) ^ m7) * 8) + (u & 7);
        }

        f32x2 cA = {0.f, 0.f};

        // ---- pipelined x-projection for tt=0 ----
        f32x4 apre[2];
        {
            const float xv = xbuf[m][0];
#pragma unroll
            for (int tau = 0; tau < 2; ++tau)
#pragma unroll
                for (int r = 0; r < 4; ++r)
                    apre[tau][r] = __builtin_fmaf(xv, wx0s[tau][r], bb0s[tau][r]);
        }

#pragma unroll 1
        for (int tt = 0; tt <= TT; ++tt) {
            if (tt < TT) {
                // h0(tt-1) guaranteed by last iteration's barrier (tt=0: zeroed slot 7)
                const int rs = ((tt - 1) & 7) * (NB * 64);
                bf16x8 h0[2];
                h0[0] = *(const bf16x8*)(H0 + rs + roff[0]);
                h0[1] = *(const bf16x8*)(H0 + rs + roff[1]);

                f32x4 a[2];
#pragma unroll
                for (int tau = 0; tau < 2; ++tau) {
                    f32x4 z = {0.f, 0.f, 0.f, 0.f};
                    a[tau] = MFMA(Ah[tau][0], h0[0], apre[tau]);
                    z      = MFMA(Ah[tau][1], h0[1], z);
                    a[tau] = a[tau] + z;
                }

                const f32x2 hv = cell2(a[0], a[1], &cA);

                const int ws = (tt & 7) * (NB * 64);
                H0[ws + woff[0]] = f32_to_bf16_rne(hv[0]);
                H0[ws + woff[1]] = f32_to_bf16_rne(hv[1]);

                // ---- pipelined x-projection for tt+1: issues while the
                //      ds_writes retire, shortening the pre-barrier drain ----
                if (tt + 1 < TT) {
                    const float xn = xbuf[m][tt + 1];
#pragma unroll
                    for (int tau = 0; tau < 2; ++tau)
#pragma unroll
                        for (int r = 0; r < 4; ++r)
                            apre[tau][r] = __builtin_fmaf(xn, wx0s[tau][r], bb0s[tau][r]);
                }
            }
            asm volatile("s_waitcnt lgkmcnt(0)" ::: "memory");
            __builtin_amdgcn_s_barrier();
            asm volatile("" ::: "memory");
        }
    } else {
        // ===== L1 waves: units [8u,8u+8), skewed one step: iter tt computes h1(tt-1) =====
        const int uW = wv - 8;
        bf16x8 Ah[2][4];     // [tau][kt]: kt0-1 Wih1 (eats h0), kt2-3 Whh1 (eats h1)
        f32x4 bb1s[2];
        int woff[2], uu[2];
#pragma unroll
        for (int tau = 0; tau < 2; ++tau) {
            const int rowA = 64 * gate_m + 8 * uW + 4 * tau + (m >> 2);
#pragma unroll
            for (int kt = 0; kt < 2; ++kt)
                build_frag_scaled(&Wih1[rowA * HH + kt * 32 + q * 8], scA, Ah[tau][kt]);
#pragma unroll
            for (int kt = 0; kt < 2; ++kt)
                build_frag_scaled(&Whh1[rowA * HH + kt * 32 + q * 8], scA, Ah[tau][2 + kt]);
#pragma unroll
            for (int r = 0; r < 4; ++r) {
                const int row = 64 * r + 8 * uW + 4 * tau + q;
                const float sc = (r == 2) ? SC_G : SC_IFO;
                bb1s[tau][r] = (bih1[row] + bhh1[row]) * sc;
            }
            const int u = 8 * uW + 4 * tau + q;
            uu[tau]   = u;
            woff[tau] = m * 64 + (((u >> 3) ^ m7) * 8) + (u & 7);
        }

        f32x2 c1v = {0.f, 0.f};

#pragma unroll 1
        for (int tt = 0; tt <= TT; ++tt) {
            if (tt >= 1) {
                const int tm = tt - 1;          // computing h1(tm)
                // h0(tm): written by L0 in iteration tm (1 barrier ago)
                // h1(tm-1): written by L1 in iteration tm (1 barrier ago); tm=0 -> zeroed
                const int rs0 = (tm & 7) * (NB * 64);
                const int rs1 = ((tm - 1) & 1) * (NB * 64);
                bf16x8 h0[2], h1[2];
                h0[0] = *(const bf16x8*)(H0 + rs0 + roff[0]);
                h0[1] = *(const bf16x8*)(H0 + rs0 + roff[1]);
                h1[0] = *(const bf16x8*)(H1 + rs1 + roff[0]);
                h1[1] = *(const bf16x8*)(H1 + rs1 + roff[1]);

                f32x4 a[2];
#pragma unroll
                for (int tau = 0; tau < 2; ++tau) {
                    f32x4 p = bb1s[tau];
                    f32x4 s = {0.f, 0.f, 0.f, 0.f};
                    p = MFMA(Ah[tau][0], h0[0], p);        // Wih1 . h0(tm)
                    p = MFMA(Ah[tau][1], h0[1], p);
                    s = MFMA(Ah[tau][2], h1[0], s);        // Whh1 . h1(tm-1)
                    s = MFMA(Ah[tau][3], h1[1], s);
                    a[tau] = p + s;                        // 2+2 tree: chain depth 2
                }

                const f32x2 hv = cell2(a[0], a[1], &c1v);
                if (tm == TT - 1) {                 // exact fp32 h1(T-1) for FC
                    h1fin[uu[0]][m] = hv[0];
                    h1fin[uu[1]][m] = hv[1];
                }
                const int ws = (tm & 1) * (NB * 64);
                H1[ws + woff[0]] = f32_to_bf16_rne(hv[0]);
                H1[ws + woff[1]] = f32_to_bf16_rne(hv[1]);
            }
            asm volatile("s_waitcnt lgkmcnt(0)" ::: "memory");
            __builtin_amdgcn_s_barrier();
            asm volatile("" ::: "memory");
        }
    }

    __syncthreads();

    // ---- FC epilogue: out[b] = h1(T-1)[b] . Wfc + bfc ----
    if (tid < NB) {
        float sacc = bfc[0];
#pragma unroll
        for (int u = 0; u < HH; ++u) sacc = fmaf(h1fin[u][tid], Wfc[u], sacc);
        out[b0 + tid] = sacc;
    }
}

extern "C" void kernel_launch(void* const* d_in, const int* in_sizes, int n_in,
                              void* d_out, int out_size, void* d_ws, size_t ws_size,
                              hipStream_t stream) {
    const float* x    = (const float*)d_in[0];
    const float* Wih0 = (const float*)d_in[1];
    const float* Whh0 = (const float*)d_in[2];
    const float* bih0 = (const float*)d_in[3];
    const float* bhh0 = (const float*)d_in[4];
    const float* Wih1 = (const float*)d_in[5];
    const float* Whh1 = (const float*)d_in[6];
    const float* bih1 = (const float*)d_in[7];
    const float* bhh1 = (const float*)d_in[8];
    const float* Wfc  = (const float*)d_in[9];
    const float* bfc  = (const float*)d_in[10];

    lstm_1t_kernel<<<dim3(4096 / NB), dim3(1024), 0, stream>>>(
        x, Wih0, Whh0, bih0, bhh0, Wih1, Whh1, bih1, bhh1, Wfc, bfc, (float*)d_out);
}